// Round 5
// baseline (463.582 us; speedup 1.0000x reference)
//
#include <hip/hip_runtime.h>

#define GN 8192
#define IN_DIM 512
#define ODIM 64
#define SLOPE 0.2f
#define JSPLIT 16
#define JCH (GN / JSPLIT)      // 512 cols per j-split
#define LSTRIDE 68             // LDS row stride in bytes (17 words, conflict-free)

typedef __attribute__((ext_vector_type(4))) float  f32x4;
typedef __attribute__((ext_vector_type(4))) int    i32x4;
typedef __attribute__((ext_vector_type(8))) short  bf16x8;
typedef __attribute__((ext_vector_type(4))) unsigned short u16x4;

static __device__ __forceinline__ float bf2f(unsigned short u) {
    return __uint_as_float(((unsigned)u) << 16);
}
static __device__ __forceinline__ unsigned short f2bf(float f) {
    union { float f; unsigned u; } c; c.f = f;
    unsigned b = c.u;
    return (unsigned short)((b + 0x7fffu + ((b >> 16) & 1u)) >> 16);  // RNE
}

// load 8 contiguous elements as bf16x8, from either wire dtype
static __device__ __forceinline__ bf16x8 load8(const void* p, size_t off, int f32) {
    if (f32) {
        f32x4 lo = *(const f32x4*)((const float*)p + off);
        f32x4 hi = *(const f32x4*)((const float*)p + off + 4);
        bf16x8 r;
        #pragma unroll
        for (int q = 0; q < 4; ++q) {
            r[q]     = (short)f2bf(lo[q]);
            r[4 + q] = (short)f2bf(hi[q]);
        }
        return r;
    }
    return *(const bf16x8*)((const ushort*)p + off);
}

// Kernel 1 (MFMA GEMM): Wh = x@W^T + epilogue: WhT bf16 [dim][row], s, d,
// dmax (atomicMax), dflag (per-wave dtype self-detect).
// A-frag: m=lane&15, k=quad*8+j. B-frag: n=lane&15, k=quad*8+j.
// C/D:    col=lane&15, row=quad*4+reg.
extern "C" __global__ __launch_bounds__(256)
void gat_proj(const void* __restrict__ x_, const void* __restrict__ W_,
              const void* __restrict__ as_, const void* __restrict__ ad_,
              ushort* __restrict__ WhT, float* __restrict__ s_arr,
              float* __restrict__ d_arr, int* __restrict__ dmax_bits,
              int* __restrict__ dflag)
{
    const int wave = threadIdx.x >> 6;
    const int lane = threadIdx.x & 63;
    // per-wave dtype self-detect: f32 N(0,1) words have exp field ~[97,134]
    unsigned xw = ((const unsigned*)x_)[lane];
    unsigned ef = (xw >> 23) & 0xffu;
    unsigned long long vt = __ballot(ef > 60u && ef < 180u);
    const int f32 = (__popcll(vt) >= 32) ? 1 : 0;
    if (blockIdx.x == 0 && threadIdx.x == 0) *dflag = f32;

    const int quad = lane >> 4;
    const int lq   = lane & 15;
    const int i0   = blockIdx.x * 64 + wave * 16;   // wave's 16-row tile base

    f32x4 acc[4] = {{0,0,0,0},{0,0,0,0},{0,0,0,0},{0,0,0,0}};
    const size_t arow = (size_t)(i0 + lq) * IN_DIM;
    #pragma unroll 2
    for (int k0 = 0; k0 < IN_DIM; k0 += 32) {
        const int kk = k0 + quad * 8;
        bf16x8 a  = load8(x_, arow + kk, f32);
        bf16x8 b0 = load8(W_, (size_t)( 0 + lq) * IN_DIM + kk, f32);
        bf16x8 b1 = load8(W_, (size_t)(16 + lq) * IN_DIM + kk, f32);
        bf16x8 b2 = load8(W_, (size_t)(32 + lq) * IN_DIM + kk, f32);
        bf16x8 b3 = load8(W_, (size_t)(48 + lq) * IN_DIM + kk, f32);
        acc[0] = __builtin_amdgcn_mfma_f32_16x16x32_bf16(a, b0, acc[0], 0, 0, 0);
        acc[1] = __builtin_amdgcn_mfma_f32_16x16x32_bf16(a, b1, acc[1], 0, 0, 0);
        acc[2] = __builtin_amdgcn_mfma_f32_16x16x32_bf16(a, b2, acc[2], 0, 0, 0);
        acc[3] = __builtin_amdgcn_mfma_f32_16x16x32_bf16(a, b3, acc[3], 0, 0, 0);
    }
    // lane holds Wh[i0 + quad*4 + r][t*16 + lq] in acc[t][r]
    float av_s[4], av_d[4];
    #pragma unroll
    for (int t = 0; t < 4; ++t) {
        const int n = t * 16 + lq;
        av_s[t] = f32 ? ((const float*)as_)[n] : bf2f(((const ushort*)as_)[n]);
        av_d[t] = f32 ? ((const float*)ad_)[n] : bf2f(((const ushort*)ad_)[n]);
    }
    #pragma unroll
    for (int t = 0; t < 4; ++t) {
        u16x4 pk;
        #pragma unroll
        for (int r = 0; r < 4; ++r) pk[r] = f2bf(acc[t][r]);
        *(u16x4*)(WhT + (size_t)(t * 16 + lq) * GN + i0 + quad * 4) = pk;
    }
    float ps[4], pd[4];
    #pragma unroll
    for (int r = 0; r < 4; ++r) {
        float s = 0.f, d = 0.f;
        #pragma unroll
        for (int t = 0; t < 4; ++t) {
            s = fmaf(acc[t][r], av_s[t], s);
            d = fmaf(acc[t][r], av_d[t], d);
        }
        #pragma unroll
        for (int off = 1; off < 16; off <<= 1) {
            s += __shfl_xor(s, off);
            d += __shfl_xor(d, off);
        }
        ps[r] = s; pd[r] = d;
    }
    if (lq == 0) {
        float dmx = -1e30f;
        #pragma unroll
        for (int r = 0; r < 4; ++r) {
            s_arr[i0 + quad * 4 + r] = ps[r];
            d_arr[i0 + quad * 4 + r] = pd[r];
            dmx = fmaxf(dmx, pd[r]);
        }
        if (dmx > 0.f) atomicMax(dmax_bits, __float_as_int(dmx));
    }
}

// Kernel 2: fused adj-stage + mask + leaky + exp + (alpha_unnorm @ Wh).
// 2048 blocks = 128 ib x 16 js; each block owns a DISJOINT 64x512 adj tile
// (adj read exactly once, coalesced: one wave = one contiguous 2KB row).
// Masks packed into LDS (1 byte = 8 j's, row stride 17 words -> conflict-free).
// lsum computed via 5th MFMA against all-ones B (layout-independent).
extern "C" __global__ __launch_bounds__(256)
void gat_attn(const int* __restrict__ adj, const ushort* __restrict__ WhT,
              const float* __restrict__ s_arr, const float* __restrict__ d_arr,
              const int* __restrict__ dmax_bits,
              float* __restrict__ accum, float* __restrict__ lsum)
{
    __shared__ unsigned char mb[64 * LSTRIDE];
    const int ib   = blockIdx.x & 127;
    const int js   = blockIdx.x >> 7;        // 0..15
    const int wave = threadIdx.x >> 6;
    const int lane = threadIdx.x & 63;
    const int quad = lane >> 4;
    const int lq   = lane & 15;
    const int i0   = ib * 64;
    const int jbase = js * JCH;

    // ---- stage adj tile -> LDS mask bytes ----
    #pragma unroll 4
    for (int s = 0; s < 16; ++s) {
        const int r = s * 4 + wave;                         // local row 0..63
        const int* row = adj + (size_t)(i0 + r) * GN + jbase;
        i32x4 a0 = *(const i32x4*)(row + lane * 8);
        i32x4 a1 = *(const i32x4*)(row + lane * 8 + 4);
        unsigned byte = 0;
        #pragma unroll
        for (int q = 0; q < 4; ++q) {
            byte |= (a0[q] > 0 ? 1u : 0u) << q;
            byte |= (a1[q] > 0 ? 1u : 0u) << (4 + q);
        }
        mb[r * LSTRIDE + lane] = (unsigned char)byte;       // byte b covers j = jbase + b*8 + bit
    }
    __syncthreads();

    // ---- MFMA loop off LDS masks ----
    const int li = wave * 16 + lq;           // this lane's local A-row
    const int i  = i0 + li;
    const float dmax = __int_as_float(*dmax_bits);
    const float si = s_arr[i];
    const float tb = si + dmax;
    const float mi = fmaxf(tb, SLOPE * tb);  // upper bound on row logits (leaky monotone)
    f32x4 acc0 = {0,0,0,0}, acc1 = {0,0,0,0}, acc2 = {0,0,0,0}, acc3 = {0,0,0,0};
    f32x4 acc4 = {0,0,0,0};                  // row-sum accumulator (ones-MFMA)
    bf16x8 ones;
    #pragma unroll
    for (int q = 0; q < 8; ++q) ones[q] = (short)0x3F80;    // bf16 1.0

    #pragma unroll 2
    for (int it = 0; it < JCH / 32; ++it) {                 // 16 iters
        const int j0 = jbase + it * 32 + quad * 8;
        // mask byte: word at li*LSTRIDE + it*4 (aligned; stride 17 words -> 16 banks)
        unsigned bw = *(const unsigned*)(mb + li * LSTRIDE + it * 4);
        const unsigned m8 = (bw >> (quad * 8)) & 0xffu;
        f32x4 dv0 = *(const f32x4*)(d_arr + j0);
        f32x4 dv1 = *(const f32x4*)(d_arr + j0 + 4);
        bf16x8 b0 = *(const bf16x8*)(WhT + (size_t)( 0 + lq) * GN + j0);
        bf16x8 b1 = *(const bf16x8*)(WhT + (size_t)(16 + lq) * GN + j0);
        bf16x8 b2 = *(const bf16x8*)(WhT + (size_t)(32 + lq) * GN + j0);
        bf16x8 b3 = *(const bf16x8*)(WhT + (size_t)(48 + lq) * GN + j0);
        float w[8];
        #pragma unroll
        for (int q = 0; q < 4; ++q) {
            float e0 = si + dv0[q];
            e0 = fmaxf(e0, SLOPE * e0);                     // leaky
            float v0 = __expf(e0 - mi);
            w[q] = ((m8 >> q) & 1u) ? v0 : 0.f;
            float e1 = si + dv1[q];
            e1 = fmaxf(e1, SLOPE * e1);
            float v1 = __expf(e1 - mi);
            w[4 + q] = ((m8 >> (4 + q)) & 1u) ? v1 : 0.f;
        }
        bf16x8 af;
        #pragma unroll
        for (int q = 0; q < 8; ++q) af[q] = (short)f2bf(w[q]);
        acc0 = __builtin_amdgcn_mfma_f32_16x16x32_bf16(af, b0, acc0, 0, 0, 0);
        acc1 = __builtin_amdgcn_mfma_f32_16x16x32_bf16(af, b1, acc1, 0, 0, 0);
        acc2 = __builtin_amdgcn_mfma_f32_16x16x32_bf16(af, b2, acc2, 0, 0, 0);
        acc3 = __builtin_amdgcn_mfma_f32_16x16x32_bf16(af, b3, acc3, 0, 0, 0);
        acc4 = __builtin_amdgcn_mfma_f32_16x16x32_bf16(af, ones, acc4, 0, 0, 0);
    }
    // C/D: col=lq, row=quad*4+r. acc4: every col holds the row sum.
    const int orow = i0 + wave * 16 + quad * 4;
    if (lq == 0) {
        #pragma unroll
        for (int r = 0; r < 4; ++r) atomicAdd(&lsum[orow + r], acc4[r]);
    }
    #pragma unroll
    for (int r = 0; r < 4; ++r) {
        atomicAdd(&accum[(size_t)(orow + r) * ODIM +  0 + lq], acc0[r]);
        atomicAdd(&accum[(size_t)(orow + r) * ODIM + 16 + lq], acc1[r]);
        atomicAdd(&accum[(size_t)(orow + r) * ODIM + 32 + lq], acc2[r]);
        atomicAdd(&accum[(size_t)(orow + r) * ODIM + 48 + lq], acc3[r]);
    }
}

// Kernel 3: out = (accum / lsum), dtype per flag
extern "C" __global__ __launch_bounds__(256)
void gat_final(const float* __restrict__ accum, const float* __restrict__ lsum,
               const int* __restrict__ flag, void* __restrict__ out)
{
    const int idx = blockIdx.x * 256 + threadIdx.x;
    const float v = accum[idx] / lsum[idx >> 6];
    if (*flag) ((float*)out)[idx] = v;
    else       ((ushort*)out)[idx] = f2bf(v);
}

extern "C" void kernel_launch(void* const* d_in, const int* in_sizes, int n_in,
                              void* d_out, int out_size, void* d_ws, size_t ws_size,
                              hipStream_t stream)
{
    const void* x     = d_in[0];
    const int*  adj   = (const int*)d_in[1];
    const void* W     = d_in[2];
    const void* a_src = d_in[3];
    const void* a_dst = d_in[4];

    char* ws = (char*)d_ws;
    size_t off = 0;
    float* accum = (float*)(ws + off);  off += (size_t)GN * ODIM * 4;      // 2 MB
    float* lsum  = (float*)(ws + off);  off += (size_t)GN * 4;             // 32 KB
    int* dmax_bits = (int*)(ws + off);  off += 128;
    size_t zero_bytes = off;                                               // zero through dmax
    int* dflag = (int*)(ws + off);      off += 128;                        // written by gat_proj
    float* s_arr = (float*)(ws + off);  off += (size_t)GN * 4;
    float* d_arr = (float*)(ws + off);  off += (size_t)GN * 4;
    ushort* WhT  = (ushort*)(ws + off); off += (size_t)ODIM * GN * 2;      // 1 MB

    hipMemsetAsync(ws, 0, zero_bytes, stream);
    gat_proj<<<GN / 64, 256, 0, stream>>>(x, W, a_src, a_dst,
                                          WhT, s_arr, d_arr, dmax_bits, dflag);
    gat_attn<<<128 * JSPLIT, 256, 0, stream>>>(adj, WhT, s_arr, d_arr,
                                               dmax_bits, accum, lsum);
    gat_final<<<GN * ODIM / 256, 256, 0, stream>>>(accum, lsum, dflag, d_out);
}

// Round 6
// 441.044 us; speedup vs baseline: 1.0511x; 1.0511x over previous
//
#include <hip/hip_runtime.h>

#define GN 8192
#define IN_DIM 512
#define ODIM 64
#define SLOPE 0.2f
#define JSPLIT 16
#define JCH (GN / JSPLIT)      // 512 cols per tile
#define LSTRIDE 68             // LDS mask row stride in bytes (17 words -> conflict-free)
#define NTILE 4                // tiles per persistent block (same ib, js stride 4)

typedef __attribute__((ext_vector_type(4))) float  f32x4;
typedef __attribute__((ext_vector_type(4))) int    i32x4;
typedef __attribute__((ext_vector_type(8))) short  bf16x8;
typedef __attribute__((ext_vector_type(4))) unsigned short u16x4;

static __device__ __forceinline__ float bf2f(unsigned short u) {
    return __uint_as_float(((unsigned)u) << 16);
}
static __device__ __forceinline__ unsigned short f2bf(float f) {
    union { float f; unsigned u; } c; c.f = f;
    unsigned b = c.u;
    return (unsigned short)((b + 0x7fffu + ((b >> 16) & 1u)) >> 16);  // RNE
}

// load 8 contiguous elements as bf16x8, from either wire dtype
static __device__ __forceinline__ bf16x8 load8(const void* p, size_t off, int f32) {
    if (f32) {
        f32x4 lo = *(const f32x4*)((const float*)p + off);
        f32x4 hi = *(const f32x4*)((const float*)p + off + 4);
        bf16x8 r;
        #pragma unroll
        for (int q = 0; q < 4; ++q) {
            r[q]     = (short)f2bf(lo[q]);
            r[4 + q] = (short)f2bf(hi[q]);
        }
        return r;
    }
    return *(const bf16x8*)((const ushort*)p + off);
}

// Kernel 1 (MFMA GEMM): Wh = x@W^T + epilogue: WhT bf16 [dim][row], s, d,
// dmax (atomicMax), dflag (per-wave dtype self-detect).
extern "C" __global__ __launch_bounds__(256)
void gat_proj(const void* __restrict__ x_, const void* __restrict__ W_,
              const void* __restrict__ as_, const void* __restrict__ ad_,
              ushort* __restrict__ WhT, float* __restrict__ s_arr,
              float* __restrict__ d_arr, int* __restrict__ dmax_bits,
              int* __restrict__ dflag)
{
    const int wave = threadIdx.x >> 6;
    const int lane = threadIdx.x & 63;
    unsigned xw = ((const unsigned*)x_)[lane];
    unsigned ef = (xw >> 23) & 0xffu;
    unsigned long long vt = __ballot(ef > 60u && ef < 180u);
    const int f32 = (__popcll(vt) >= 32) ? 1 : 0;
    if (blockIdx.x == 0 && threadIdx.x == 0) *dflag = f32;

    const int quad = lane >> 4;
    const int lq   = lane & 15;
    const int i0   = blockIdx.x * 64 + wave * 16;

    f32x4 acc[4] = {{0,0,0,0},{0,0,0,0},{0,0,0,0},{0,0,0,0}};
    const size_t arow = (size_t)(i0 + lq) * IN_DIM;
    #pragma unroll 2
    for (int k0 = 0; k0 < IN_DIM; k0 += 32) {
        const int kk = k0 + quad * 8;
        bf16x8 a  = load8(x_, arow + kk, f32);
        bf16x8 b0 = load8(W_, (size_t)( 0 + lq) * IN_DIM + kk, f32);
        bf16x8 b1 = load8(W_, (size_t)(16 + lq) * IN_DIM + kk, f32);
        bf16x8 b2 = load8(W_, (size_t)(32 + lq) * IN_DIM + kk, f32);
        bf16x8 b3 = load8(W_, (size_t)(48 + lq) * IN_DIM + kk, f32);
        acc[0] = __builtin_amdgcn_mfma_f32_16x16x32_bf16(a, b0, acc[0], 0, 0, 0);
        acc[1] = __builtin_amdgcn_mfma_f32_16x16x32_bf16(a, b1, acc[1], 0, 0, 0);
        acc[2] = __builtin_amdgcn_mfma_f32_16x16x32_bf16(a, b2, acc[2], 0, 0, 0);
        acc[3] = __builtin_amdgcn_mfma_f32_16x16x32_bf16(a, b3, acc[3], 0, 0, 0);
    }
    float av_s[4], av_d[4];
    #pragma unroll
    for (int t = 0; t < 4; ++t) {
        const int n = t * 16 + lq;
        av_s[t] = f32 ? ((const float*)as_)[n] : bf2f(((const ushort*)as_)[n]);
        av_d[t] = f32 ? ((const float*)ad_)[n] : bf2f(((const ushort*)ad_)[n]);
    }
    #pragma unroll
    for (int t = 0; t < 4; ++t) {
        u16x4 pk;
        #pragma unroll
        for (int r = 0; r < 4; ++r) pk[r] = f2bf(acc[t][r]);
        *(u16x4*)(WhT + (size_t)(t * 16 + lq) * GN + i0 + quad * 4) = pk;
    }
    float ps[4], pd[4];
    #pragma unroll
    for (int r = 0; r < 4; ++r) {
        float s = 0.f, d = 0.f;
        #pragma unroll
        for (int t = 0; t < 4; ++t) {
            s = fmaf(acc[t][r], av_s[t], s);
            d = fmaf(acc[t][r], av_d[t], d);
        }
        #pragma unroll
        for (int off = 1; off < 16; off <<= 1) {
            s += __shfl_xor(s, off);
            d += __shfl_xor(d, off);
        }
        ps[r] = s; pd[r] = d;
    }
    if (lq == 0) {
        float dmx = -1e30f;
        #pragma unroll
        for (int r = 0; r < 4; ++r) {
            s_arr[i0 + quad * 4 + r] = ps[r];
            d_arr[i0 + quad * 4 + r] = pd[r];
            dmx = fmaxf(dmx, pd[r]);
        }
        if (dmx > 0.f) atomicMax(dmax_bits, __float_as_int(dmx));
    }
}

// Kernel 2: persistent fused attention. 512 blocks; block b owns rows
// ib=b&127 (fixed!) and 4 j-tiles js = (b>>7) + 4t. Software-pipelined adj
// staging: chunk loads for tile t+1 issue during compute of tile t into a
// 3-deep register ring, packed to the alternate LDS mask buffer 2 iters
// later (compiler emits fine-grained vmcnt(N) before each use, so loads
// stay in flight across the compute). b-frags prefetched 1 iter ahead and
// issued BEFORE each adj chunk so their vmcnt wait never drains adj loads
// (in-order retirement). Accumulators persist across tiles: atomics 4x cut.
extern "C" __global__ __launch_bounds__(256)
void gat_attn(const int* __restrict__ adj, const ushort* __restrict__ WhT,
              const float* __restrict__ s_arr, const float* __restrict__ d_arr,
              const int* __restrict__ dmax_bits,
              float* __restrict__ accum, float* __restrict__ lsum)
{
    __shared__ unsigned char mb[2][64 * LSTRIDE];
    const int b    = blockIdx.x;        // 0..511
    const int ib   = b & 127;
    const int js0  = b >> 7;            // 0..3
    const int wave = threadIdx.x >> 6;
    const int lane = threadIdx.x & 63;
    const int quad = lane >> 4;
    const int lq   = lane & 15;
    const int i0   = ib * 64;
    const int li   = wave * 16 + lq;    // lane's local A-row
    const int i    = i0 + li;
    const float dmax = __int_as_float(*dmax_bits);
    const float si = s_arr[i];
    const float tbv = si + dmax;
    const float mi = fmaxf(tbv, SLOPE * tbv);   // row-logit upper bound

    const size_t adjbase = (size_t)i0 * GN + lane * 8;

    i32x4 ra[3], rb[3];
    auto pack = [&](const i32x4& va, const i32x4& vb, int c, int bufsel) {
        unsigned byte = 0;
        #pragma unroll
        for (int q = 0; q < 4; ++q) {
            byte |= (va[q] > 0 ? 1u : 0u) << q;
            byte |= (vb[q] > 0 ? 1u : 0u) << (4 + q);
        }
        mb[bufsel][(c * 4 + wave) * LSTRIDE + lane] = (unsigned char)byte;
    };

    f32x4 acc0 = {0,0,0,0}, acc1 = {0,0,0,0}, acc2 = {0,0,0,0}, acc3 = {0,0,0,0};
    f32x4 acc4 = {0,0,0,0};             // row-sum via ones-MFMA
    bf16x8 ones;
    #pragma unroll
    for (int q = 0; q < 8; ++q) ones[q] = (short)0x3F80;

    // ---- prologue: stage tile 0 -> mb[0] (3-deep pipelined) ----
    {
        const int jb = js0 * JCH;
        #pragma unroll
        for (int c = 0; c < 16; ++c) {
            const int* rp = adj + adjbase + (size_t)(c * 4 + wave) * GN + jb;
            ra[c % 3] = ((const i32x4*)rp)[0];
            rb[c % 3] = ((const i32x4*)rp)[1];
            if (c >= 2) pack(ra[(c - 2) % 3], rb[(c - 2) % 3], c - 2, 0);
        }
        pack(ra[14 % 3], rb[14 % 3], 14, 0);
        pack(ra[15 % 3], rb[15 % 3], 15, 0);
    }
    __syncthreads();

    // preload b-frags/dv for tile 0, iter 0
    int jpre = js0 * JCH + quad * 8;
    f32x4 dv0 = *(const f32x4*)(d_arr + jpre);
    f32x4 dv1 = *(const f32x4*)(d_arr + jpre + 4);
    bf16x8 b0 = *(const bf16x8*)(WhT + (size_t)( 0 + lq) * GN + jpre);
    bf16x8 b1 = *(const bf16x8*)(WhT + (size_t)(16 + lq) * GN + jpre);
    bf16x8 b2 = *(const bf16x8*)(WhT + (size_t)(32 + lq) * GN + jpre);
    bf16x8 b3 = *(const bf16x8*)(WhT + (size_t)(48 + lq) * GN + jpre);

    #pragma unroll 1
    for (int t = 0; t < NTILE; ++t) {
        const int jb   = (js0 + 4 * t) * JCH;
        const int jbn  = jb + 4 * JCH;          // next tile's column base
        const bool more = (t < NTILE - 1);
        const int buf  = t & 1, nbuf = buf ^ 1;

        #pragma unroll
        for (int it = 0; it < 16; ++it) {
            // 1) prefetch compute operands for next iter (older than this
            //    iter's adj chunk -> their wait never drains adj loads)
            const int jn = (it < 15) ? (jb + (it + 1) * 32 + quad * 8)
                                     : (more ? (jbn + quad * 8) : (jb + quad * 8));
            f32x4 ndv0 = *(const f32x4*)(d_arr + jn);
            f32x4 ndv1 = *(const f32x4*)(d_arr + jn + 4);
            bf16x8 nb0 = *(const bf16x8*)(WhT + (size_t)( 0 + lq) * GN + jn);
            bf16x8 nb1 = *(const bf16x8*)(WhT + (size_t)(16 + lq) * GN + jn);
            bf16x8 nb2 = *(const bf16x8*)(WhT + (size_t)(32 + lq) * GN + jn);
            bf16x8 nb3 = *(const bf16x8*)(WhT + (size_t)(48 + lq) * GN + jn);
            // 2) issue next-tile adj chunk into the register ring
            if (more) {
                const int* rp = adj + adjbase + (size_t)(it * 4 + wave) * GN + jbn;
                ra[it % 3] = ((const i32x4*)rp)[0];
                rb[it % 3] = ((const i32x4*)rp)[1];
            }
            // 3) pack chunk it-2 (waits only chunks <= it-2; it-1, it stay in flight)
            if (more && it >= 2)
                pack(ra[(it - 2) % 3], rb[(it - 2) % 3], it - 2, nbuf);
            // 4) compute iter it from current-tile masks + preloaded b/dv
            unsigned bw = *(const unsigned*)(&mb[buf][li * LSTRIDE + it * 4]);
            const unsigned m8 = (bw >> (quad * 8)) & 0xffu;
            float w[8];
            #pragma unroll
            for (int q = 0; q < 4; ++q) {
                float e0 = si + dv0[q];
                e0 = fmaxf(e0, SLOPE * e0);
                float v0 = __expf(e0 - mi);
                w[q] = ((m8 >> q) & 1u) ? v0 : 0.f;
                float e1 = si + dv1[q];
                e1 = fmaxf(e1, SLOPE * e1);
                float v1 = __expf(e1 - mi);
                w[4 + q] = ((m8 >> (4 + q)) & 1u) ? v1 : 0.f;
            }
            bf16x8 af;
            #pragma unroll
            for (int q = 0; q < 8; ++q) af[q] = (short)f2bf(w[q]);
            acc0 = __builtin_amdgcn_mfma_f32_16x16x32_bf16(af, b0, acc0, 0, 0, 0);
            acc1 = __builtin_amdgcn_mfma_f32_16x16x32_bf16(af, b1, acc1, 0, 0, 0);
            acc2 = __builtin_amdgcn_mfma_f32_16x16x32_bf16(af, b2, acc2, 0, 0, 0);
            acc3 = __builtin_amdgcn_mfma_f32_16x16x32_bf16(af, b3, acc3, 0, 0, 0);
            acc4 = __builtin_amdgcn_mfma_f32_16x16x32_bf16(af, ones, acc4, 0, 0, 0);
            // roll prefetched operands
            dv0 = ndv0; dv1 = ndv1; b0 = nb0; b1 = nb1; b2 = nb2; b3 = nb3;
        }
        if (more) {
            pack(ra[14 % 3], rb[14 % 3], 14, nbuf);
            pack(ra[15 % 3], rb[15 % 3], 15, nbuf);
        }
        __syncthreads();
    }

    // epilogue: C/D col=lq, row=quad*4+r; acc4 holds row sums in every col
    const int orow = i0 + wave * 16 + quad * 4;
    if (lq == 0) {
        #pragma unroll
        for (int r = 0; r < 4; ++r) atomicAdd(&lsum[orow + r], acc4[r]);
    }
    #pragma unroll
    for (int r = 0; r < 4; ++r) {
        atomicAdd(&accum[(size_t)(orow + r) * ODIM +  0 + lq], acc0[r]);
        atomicAdd(&accum[(size_t)(orow + r) * ODIM + 16 + lq], acc1[r]);
        atomicAdd(&accum[(size_t)(orow + r) * ODIM + 32 + lq], acc2[r]);
        atomicAdd(&accum[(size_t)(orow + r) * ODIM + 48 + lq], acc3[r]);
    }
}

// Kernel 3: out = (accum / lsum), dtype per flag
extern "C" __global__ __launch_bounds__(256)
void gat_final(const float* __restrict__ accum, const float* __restrict__ lsum,
               const int* __restrict__ flag, void* __restrict__ out)
{
    const int idx = blockIdx.x * 256 + threadIdx.x;
    const float v = accum[idx] / lsum[idx >> 6];
    if (*flag) ((float*)out)[idx] = v;
    else       ((ushort*)out)[idx] = f2bf(v);
}

extern "C" void kernel_launch(void* const* d_in, const int* in_sizes, int n_in,
                              void* d_out, int out_size, void* d_ws, size_t ws_size,
                              hipStream_t stream)
{
    const void* x     = d_in[0];
    const int*  adj   = (const int*)d_in[1];
    const void* W     = d_in[2];
    const void* a_src = d_in[3];
    const void* a_dst = d_in[4];

    char* ws = (char*)d_ws;
    size_t off = 0;
    float* accum = (float*)(ws + off);  off += (size_t)GN * ODIM * 4;      // 2 MB
    float* lsum  = (float*)(ws + off);  off += (size_t)GN * 4;             // 32 KB
    int* dmax_bits = (int*)(ws + off);  off += 128;
    size_t zero_bytes = off;                                               // zero through dmax
    int* dflag = (int*)(ws + off);      off += 128;                        // written by gat_proj
    float* s_arr = (float*)(ws + off);  off += (size_t)GN * 4;
    float* d_arr = (float*)(ws + off);  off += (size_t)GN * 4;
    ushort* WhT  = (ushort*)(ws + off); off += (size_t)ODIM * GN * 2;      // 1 MB

    hipMemsetAsync(ws, 0, zero_bytes, stream);
    gat_proj<<<GN / 64, 256, 0, stream>>>(x, W, a_src, a_dst,
                                          WhT, s_arr, d_arr, dmax_bits, dflag);
    gat_attn<<<512, 256, 0, stream>>>(adj, WhT, s_arr, d_arr,
                                      dmax_bits, accum, lsum);
    gat_final<<<GN * ODIM / 256, 256, 0, stream>>>(accum, lsum, dflag, d_out);
}